// Round 1
// baseline (418.788 us; speedup 1.0000x reference)
//
#include <hip/hip_runtime.h>

// Problem constants (from reference): N_T=5, 32x32 grid, N=1024, batch=4.
#define NT   5
#define NY   32
#define NX   32
#define NN   1024          // N = NY*NX
#define QDIM 5120          // NT * NN
#define NB   4
#define G    8             // rows per block (all share the same ry band)

// Native clang vector type — required by __builtin_nontemporal_store.
typedef float vfloat4 __attribute__((ext_vector_type(4)));

// Canonical stencil offset order (matches reference's offs list):
// 0:(0,0) 1:(0,1) 2:(0,-1) 3:(1,0) 4:(-1,0) 5:(1,1) 6:(1,-1) 7:(-1,1) 8:(-1,-1)
__device__ const int c_oy[9] = {0, 0, 0, 1, -1, 1, 1, -1, -1};
__device__ const int c_ox[9] = {0, 1, -1, 0, 0, 1, -1, 1, -1};

// Stencil coefficients of M = I + A for node n, time t, batch b.
// Out-of-grid neighbor coefficients zeroed (matches VALID in reference).
__device__ __forceinline__ void stencil9(const float* __restrict__ kap,
                                         const float* __restrict__ m,
                                         const float* __restrict__ H,
                                         int b, int t, int n, float s[9]) {
    // Layouts: kappa (NB,1,NN,NT); m (NB,2,NN,NT); H (NB,2,2,NN,NT)
    float k   = kap[((size_t)b * NN + n) * NT + t];
    float mx  = m[(((size_t)b * 2 + 0) * NN + n) * NT + t];
    float my  = m[(((size_t)b * 2 + 1) * NN + n) * NT + t];
    float H11 = H[((((size_t)b * 2 + 0) * 2 + 0) * NN + n) * NT + t];
    float H01 = H[((((size_t)b * 2 + 0) * 2 + 1) * NN + n) * NT + t];
    float H10 = H[((((size_t)b * 2 + 1) * 2 + 0) * NN + n) * NT + t];
    float H22 = H[((((size_t)b * 2 + 1) * 2 + 1) * NN + n) * NT + t];
    float cc = 0.25f * (H01 + H10);                  // H12/(2 DX DY), DX=DY=1
    s[0] = 1.0f + k * k + 2.0f * H11 + 2.0f * H22;   // diag of M = 1 + c0
    s[1] =  0.5f * mx - H11;    // (0,+1)
    s[2] = -0.5f * mx - H11;    // (0,-1)
    s[3] =  0.5f * my - H22;    // (+1,0)
    s[4] = -0.5f * my - H22;    // (-1,0)
    s[5] = -cc;                 // (+1,+1)
    s[6] =  cc;                 // (+1,-1)
    s[7] =  cc;                 // (-1,+1)
    s[8] = -cc;                 // (-1,-1)
    int y = n >> 5, x = n & 31;
    if (x == NX - 1) { s[1] = 0.f; s[5] = 0.f; s[7] = 0.f; }
    if (x == 0)      { s[2] = 0.f; s[6] = 0.f; s[8] = 0.f; }
    if (y == NY - 1) { s[3] = 0.f; s[5] = 0.f; s[6] = 0.f; }
    if (y == 0)      { s[4] = 0.f; s[7] = 0.f; s[8] = 0.f; }
}

// One 256-thread block per G=8 consecutive output rows (same b, t, same ry).
// Key change vs previous version: amortize the per-row setup (LDS zeroing,
// 2 barriers, 11-thread stencil latency) over 8x the stored bytes, and give
// each thread 40 independent nontemporal stores (deep store pipeline) instead
// of 5. Row nonzeros live only in grid-rows ry-2..ry+2, so we stage a compact
// [G][3 col-blocks][5 band rows][32] image (15 KB) instead of 8 full rows.
// Every byte of Q is written exactly once; no memset pass.
__global__ __launch_bounds__(256) void spde_fused_g8(const float* __restrict__ kap,
                                                     const float* __restrict__ m,
                                                     const float* __restrict__ H,
                                                     float* __restrict__ Q) {
    const int oy[9] = {0, 0, 0, 1, -1, 1, 1, -1, -1};
    const int ox[9] = {0, 1, -1, 0, 0, 1, -1, 1, -1};

    int blk = blockIdx.x;                 // 0 .. NB*NT*(NN/G)-1 = 2559
    int b   = blk / (NT * (NN / G));
    int rem = blk - b * (NT * (NN / G));
    int t   = rem >> 7;                   // / (NN/G) = /128
    int grp = rem & 127;
    int base = grp << 3;                  // first row index r of this group
    int ry = base >> 5;                   // same for all 8 rows (8 | base)
    int rxb = base & 31;                  // x of row j is rxb + j (< 32)
    int tid = threadIdx.x;

    // band[((j*3 + z)*5 + br)*32 + cx]: value of Q[row base+j, col-block
    // (t-1+z), grid-row (ry-2+br), grid-col cx]. Rows outside the band are 0.
    __shared__ float band[G * 3 * 5 * 32];    // 15360 B
    __shared__ float sk[G][9][9];    // stencil of M[t] at 9 neighbors, per row
    __shared__ float moff[G][2][9];  // -M[t-1][r,:], -M[t+1][r,:], per row

    // ---- Phase 0/1: zero band; threads 0..87 compute the 88 stencils ----
    {
        vfloat4 z4 = {0.f, 0.f, 0.f, 0.f};
        vfloat4* p = (vfloat4*)band;          // 960 float4 slots
#pragma unroll
        for (int w = 0; w < 4; ++w) {
            int idx = tid + 256 * w;
            if (idx < (G * 3 * 5 * 32) / 4) p[idx] = z4;
        }
    }
    if (tid < G * 11) {
        int j = tid / 11, u = tid - j * 11;
        int rj = base + j;
        if (u < 9) {
            int ky = ry + c_oy[u], kx = (rxb + j) + c_ox[u];
            bool valid = ((unsigned)ky < NY) && ((unsigned)kx < NX);
            int k = valid ? (ky * NX + kx) : rj;  // clamp; killed by sk[j][0]==0
            float s[9];
            stencil9(kap, m, H, b, t, k, s);
#pragma unroll
            for (int e = 0; e < 9; ++e)
                sk[j][u][(oy[e] + 1) * 3 + (ox[e] + 1)] = s[e];
        } else if (u == 9) {
            float s[9] = {0, 0, 0, 0, 0, 0, 0, 0, 0};
            if (t >= 1) stencil9(kap, m, H, b, t - 1, rj, s);
#pragma unroll
            for (int e = 0; e < 9; ++e) moff[j][0][e] = -s[e];
        } else {
            float s[9] = {0, 0, 0, 0, 0, 0, 0, 0, 0};
            if (t <= NT - 2) stencil9(kap, m, H, b, t + 1, rj, s);
#pragma unroll
            for (int e = 0; e < 9; ++e) moff[j][1][e] = -s[e];
        }
    }
    __syncthreads();

    // ---- Phase 2: scatter the 8*43 nonzero entries into the band image ----
    for (int it = tid; it < G * 43; it += 256) {
        int j = it / 43, q = it - j * 43;
        int rxj = rxb + j;
        if (q < 25) {
            // Diag block (z=1): entry (dy,dx) of row r of MM[t] (+I interior)
            int dy = q / 5 - 2, dx = q % 5 - 2;
            float a = 0.f;
#pragma unroll
            for (int d1 = 0; d1 < 9; ++d1) {
                int dy2 = dy - oy[d1], dx2 = dx - ox[d1];
                if (dy2 >= -1 && dy2 <= 1 && dx2 >= -1 && dx2 <= 1) {
                    a += sk[j][0][(oy[d1] + 1) * 3 + (ox[d1] + 1)]
                       * sk[j][d1][(dy2 + 1) * 3 + (dx2 + 1)];
                }
            }
            if (q == 12 && t >= 1 && t <= NT - 2) a += 1.0f;  // MM + I interior
            int cy = ry + dy, cx = rxj + dx;
            if ((unsigned)cy < NY && (unsigned)cx < NX)
                band[((j * 3 + 1) * 5 + (dy + 2)) * 32 + cx] = a;
        } else if (q < 34) {
            // Block t-1 (z=0): -M[t-1][r, c]; moff[j][0] is all-zero when t==0
            int d = q - 25;
            int cy = ry + c_oy[d], cx = rxj + c_ox[d];
            if ((unsigned)cy < NY && (unsigned)cx < NX)
                band[((j * 3 + 0) * 5 + (c_oy[d] + 2)) * 32 + cx] = moff[j][0][d];
        } else {
            // Block t+1 (z=2): -M[t+1][r, c]; all-zero when t==NT-1
            int d = q - 34;
            int cy = ry + c_oy[d], cx = rxj + c_ox[d];
            if ((unsigned)cy < NY && (unsigned)cx < NX)
                band[((j * 3 + 2) * 5 + (c_oy[d] + 2)) * 32 + cx] = moff[j][1][d];
        }
    }
    __syncthreads();

    // ---- Phase 3: stream 8 rows x 5120 cols; 40 float4 nt-stores/thread ----
    // Thread tid covers grid-cell (cy = tid>>3, cols 4*(tid&7)..+3) of every
    // 1024-col block; a cell is nonzero only if cy is within the 5-row band.
    int cy  = tid >> 3;                 // 0..31
    int cx4 = (tid & 7) * 4;            // 0,4,..,28
    int br  = cy - (ry - 2);
    bool inband = (unsigned)br < 5u;
    int br_c = inband ? br : 0;
    const float* bp = band + br_c * 32 + cx4;
    float* dst = Q + ((size_t)b * QDIM + (size_t)t * NN + base) * QDIM + 4 * tid;
    vfloat4 z4 = {0.f, 0.f, 0.f, 0.f};
#pragma unroll
    for (int j = 0; j < G; ++j) {
#pragma unroll
        for (int kk = 0; kk < NT; ++kk) {
            int z = kk - t + 1;                       // wave-uniform
            bool ok = ((unsigned)z < 3u) && inband;
            int z_c = ((unsigned)z < 3u) ? z : 0;
            vfloat4 v = ok ? *(const vfloat4*)(bp + (j * 3 + z_c) * 160) : z4;
            __builtin_nontemporal_store(v,
                (vfloat4*)(dst + (size_t)j * QDIM + kk * NN));
        }
    }
}

extern "C" void kernel_launch(void* const* d_in, const int* in_sizes, int n_in,
                              void* d_out, int out_size, void* d_ws, size_t ws_size,
                              hipStream_t stream) {
    const float* kap = (const float*)d_in[0];
    const float* m   = (const float*)d_in[1];
    const float* H   = (const float*)d_in[2];
    float* Q = (float*)d_out;

    int nblocks = NB * NT * (NN / G);  // 2560 blocks, 8 rows each
    spde_fused_g8<<<nblocks, 256, 0, stream>>>(kap, m, H, Q);
}